// Round 3
// baseline (1237.007 us; speedup 1.0000x reference)
//
#include <hip/hip_runtime.h>

#define HD 128   // hidden dim

typedef unsigned short ushort_t;
typedef __attribute__((ext_vector_type(8))) unsigned short us8;
typedef __attribute__((ext_vector_type(8))) short s8b;       // 8 bf16 = 4 VGPR (MFMA A/B frag)
typedef __attribute__((ext_vector_type(16))) float f32x16;   // MFMA 32x32 accumulator

// ---------------- bf16 <-> f32 ----------------
__device__ __forceinline__ float b2f(unsigned short u) {
    union { unsigned int i; float f; } v; v.i = ((unsigned int)u) << 16; return v.f;
}
__device__ __forceinline__ unsigned short f2b(float f) {
    union { float f; unsigned int i; } v; v.f = f;
    unsigned int u = v.i;
    return (unsigned short)((u + 0x7fffu + ((u >> 16) & 1u)) >> 16);  // RNE
}

__device__ __forceinline__ void load8f(const float* p, float* o) {
    float4 a = *reinterpret_cast<const float4*>(p);
    float4 b = *reinterpret_cast<const float4*>(p + 4);
    o[0]=a.x;o[1]=a.y;o[2]=a.z;o[3]=a.w;o[4]=b.x;o[5]=b.y;o[6]=b.z;o[7]=b.w;
}
__device__ __forceinline__ void load8b(const ushort_t* p, float* o) {
    us8 v = *reinterpret_cast<const us8*>(p);
#pragma unroll
    for (int j = 0; j < 8; ++j) o[j] = b2f(v[j]);
}
__device__ __forceinline__ void store8b(ushort_t* p, const float* s) {
    us8 v;
#pragma unroll
    for (int j = 0; j < 8; ++j) v[j] = f2b(s[j]);
    *reinterpret_cast<us8*>(p) = v;
}

__device__ __forceinline__ void store1(float* p, float v) { *p = v; }
__device__ __forceinline__ void store1(ushort_t* p, float v) { *p = f2b(v); }

__device__ __forceinline__ int lowerb(const int* __restrict__ a, int n, int v) {
    int lo = 0, hi = n;
    while (lo < hi) { int m = (lo + hi) >> 1; if (a[m] < v) lo = m + 1; else hi = m; }
    return lo;
}

// ---------------- CSR build ----------------
__global__ void hist_kernel(const int* __restrict__ dst, int* __restrict__ deg, int e) {
    int i = blockIdx.x * blockDim.x + threadIdx.x;
    if (i < e) atomicAdd(&deg[dst[i]], 1);
}

__global__ __launch_bounds__(1024) void scan_kernel(const int* __restrict__ deg,
                                                    int* __restrict__ rowptr,
                                                    int* __restrict__ cursor, int n) {
    const int T = 1024;
    __shared__ int ps[T];
    int tid = threadIdx.x;
    int per = (n + T - 1) / T;
    int s = tid * per;
    int e = s + per; if (e > n) e = n; if (s > n) s = n;
    int sum = 0;
    for (int i = s; i < e; ++i) sum += deg[i];
    ps[tid] = sum;
    __syncthreads();
    for (int off = 1; off < T; off <<= 1) {
        int v = (tid >= off) ? ps[tid - off] : 0;
        __syncthreads();
        ps[tid] += v;
        __syncthreads();
    }
    int run = ps[tid] - sum;
    for (int i = s; i < e; ++i) { rowptr[i] = run; cursor[i] = run; run += deg[i]; }
    if (tid == T - 1) rowptr[n] = ps[T - 1];
}

__global__ void fill_kernel(const int* __restrict__ src, const int* __restrict__ dst,
                            int* __restrict__ cursor, int* __restrict__ col, int e) {
    int i = blockIdx.x * blockDim.x + threadIdx.x;
    if (i < e) { int slot = atomicAdd(&cursor[dst[i]], 1); col[slot] = src[i]; }
}

// ---------------- W pre-pack into MFMA B-fragment order (bf16) ----------------
// Fragment order: flat idx = ((mat*4 + j)*8 + ks)*64 + lane, 8 bf16 each:
//   elem e = W[k = ks*16 + (lane>>5)*8 + e][n = mat*col_off + j*32 + (lane&31)]
__global__ void pack_kernel(const float* __restrict__ W, ushort_t* __restrict__ Wp,
                            int nmat, int ld, int mat_stride, int col_off) {
    int idx = blockIdx.x * blockDim.x + threadIdx.x;
    if (idx >= nmat * 2048) return;
    int lane = idx & 63;
    int ks = (idx >> 6) & 7;
    int j = (idx >> 9) & 3;
    int mat = idx >> 11;
    const float* Wm = W + (size_t)mat * mat_stride;
    int k0 = ks * 16 + (lane >> 5) * 8;
    int n = mat * col_off + j * 32 + (lane & 31);
    us8 o;
#pragma unroll
    for (int e = 0; e < 8; ++e) o[e] = f2b(Wm[(size_t)(k0 + e) * ld + n]);
    *reinterpret_cast<us8*>(Wp + (size_t)idx * 8) = o;
}

// ---------------- encoder: h = x @ W_enc + b_enc  (bf16 out) ----------------
__global__ void enc_kernel(const float* __restrict__ x, const float* __restrict__ W,
                           const float* __restrict__ b, ushort_t* __restrict__ h, int n) {
    int idx = blockIdx.x * blockDim.x + threadIdx.x;   // n*16 threads, 8 cols each
    if (idx >= n * 16) return;
    int node = idx >> 4, g = idx & 15;
    const float* xr = x + (size_t)node * 6;
    float xv[6];
#pragma unroll
    for (int d = 0; d < 6; ++d) xv[d] = xr[d];
    float acc[8];
    load8f(b + g * 8, acc);
#pragma unroll
    for (int d = 0; d < 6; ++d) {
        float w[8];
        load8f(W + d * HD + g * 8, w);
#pragma unroll
        for (int j = 0; j < 8; ++j) acc[j] += xv[d] * w[j];
    }
    store8b(h + (size_t)node * HD + g * 8, acc);
}

// ---------------- aggregation: z = h + sum_{in-neighbors} h  (bf16) ----------------
__global__ void agg_kernel(const ushort_t* __restrict__ h, const int* __restrict__ rowptr,
                           const int* __restrict__ col, ushort_t* __restrict__ z, int n) {
    int t = blockIdx.x * blockDim.x + threadIdx.x;     // n*16 threads
    int node = t >> 4;
    if (node >= n) return;
    int g = t & 15;
    float acc[8];
    load8b(h + (size_t)node * HD + g * 8, acc);
    int lo = rowptr[node], hi = rowptr[node + 1];
    for (int i = lo; i < hi; ++i) {
        int s = col[i];
        float v[8];
        load8b(h + (size_t)s * HD + g * 8, v);
#pragma unroll
        for (int j = 0; j < 8; ++j) acc[j] += v[j];
    }
    store8b(z + (size_t)node * HD + g * 8, acc);
}

// ---------------- MFMA GEMM: out = (relu?)(A[npad,128] @ W + b), A bf16, acc f32 ----------------
// 256 threads = 4 waves; wave owns 32 rows x 128 cols; block = 128 rows.
// Wp pre-packed (one 128x128 matrix, 32 KB) staged to LDS.
template<typename TO, bool RELU>
__global__ __launch_bounds__(256) void gemm_mfma(
    const ushort_t* __restrict__ A, const ushort_t* __restrict__ Wp,
    const float* __restrict__ bias, TO* __restrict__ out, int ldo)
{
    __shared__ s8b sW[2048];    // 32 KB
    const int tid = threadIdx.x;
    for (int i = tid; i < 2048; i += 256)
        sW[i] = reinterpret_cast<const s8b*>(Wp)[i];
    __syncthreads();

    const int lane = tid & 63;
    const int row0 = blockIdx.x * 128 + (tid >> 6) * 32;
    const int arow = row0 + (lane & 31);
    const int koff = (lane >> 5) * 8;

    // A fragments: lane holds row (arow), k = ks*16 + koff + [0..8)
    s8b a[8];
#pragma unroll
    for (int ks = 0; ks < 8; ++ks)
        a[ks] = *reinterpret_cast<const s8b*>(A + (size_t)arow * HD + ks * 16 + koff);

#pragma unroll
    for (int j = 0; j < 4; ++j) {
        f32x16 acc;
#pragma unroll
        for (int i = 0; i < 16; ++i) acc[i] = 0.f;
#pragma unroll
        for (int ks = 0; ks < 8; ++ks)
            acc = __builtin_amdgcn_mfma_f32_32x32x16_bf16(a[ks], sW[(j * 8 + ks) * 64 + lane], acc, 0, 0, 0);
        // C/D: col = lane&31 (+j*32), row = (reg&3) + 8*(reg>>2) + 4*(lane>>5)
        const int col = j * 32 + (lane & 31);
        const float bv = bias[col];
        const int rbase = row0 + 4 * (lane >> 5);
#pragma unroll
        for (int reg = 0; reg < 16; ++reg) {
            int row = rbase + (reg & 3) + 8 * (reg >> 2);
            float v = acc[reg] + bv;
            if (RELU) v = fmaxf(v, 0.f);
            store1(out + (size_t)row * ldo + col, v);
        }
    }
}

// ---------------- pooling: mean over sorted batch segments (bf16 in, bf16 out) ----------------
__global__ __launch_bounds__(128) void pool_kernel(const ushort_t* __restrict__ h,
                                                   const int* __restrict__ batch,
                                                   ushort_t* __restrict__ pooled, int n) {
    int g = blockIdx.x;
    int c = threadIdx.x;   // 128
    int start = lowerb(batch, n, g);
    int end = lowerb(batch, n, g + 1);
    float s = 0.f;
    for (int i = start; i < end; ++i) s += b2f(h[(size_t)i * HD + c]);
    int cnt = end - start; if (cnt < 1) cnt = 1;
    pooled[(size_t)g * HD + c] = f2b(s / (float)cnt);
}

// ---------------- entry ----------------
extern "C" void kernel_launch(void* const* d_in, const int* in_sizes, int n_in,
                              void* d_out, int out_size, void* d_ws, size_t ws_size,
                              hipStream_t stream) {
    const float* x      = (const float*)d_in[0];
    const int*   edge   = (const int*)d_in[1];
    const int*   batch  = (const int*)d_in[2];
    const float* W_enc  = (const float*)d_in[3];
    const float* b_enc  = (const float*)d_in[4];
    const float* W1     = (const float*)d_in[5];
    const float* b1     = (const float*)d_in[6];
    const float* W2     = (const float*)d_in[7];
    const float* b2     = (const float*)d_in[8];
    const float* W_out  = (const float*)d_in[9];
    const float* b_out  = (const float*)d_in[10];

    const int N = in_sizes[0] / 6;
    const int E = in_sizes[1] / 2;
    const int G = out_size / 256;
    const int L = in_sizes[5] / (HD * HD);
    const int Npad = ((N + 127) / 128) * 128;

    const int* srcv = edge;
    const int* dstv = edge + E;

    size_t off = 0;
    auto alloc = [&](size_t bytes) -> char* {
        char* p = (char*)d_ws + off;
        off += (bytes + 255) & ~(size_t)255;
        return p;
    };
    ushort_t* bufA   = (ushort_t*)alloc((size_t)Npad * HD * 2);
    ushort_t* bufB   = (ushort_t*)alloc((size_t)Npad * HD * 2);
    ushort_t* pooled = (ushort_t*)alloc((size_t)G * HD * 2);
    ushort_t* Wp1    = (ushort_t*)alloc((size_t)L * 16384 * 2);
    ushort_t* Wp2    = (ushort_t*)alloc((size_t)L * 16384 * 2);
    ushort_t* WpO    = (ushort_t*)alloc((size_t)2 * 16384 * 2);
    int* rowptr = (int*)alloc((size_t)(N + 1) * 4);
    int* cursor = (int*)alloc((size_t)N * 4);
    int* colidx = (int*)alloc((size_t)E * 4);
    int* deg    = (int*)alloc((size_t)N * 4);
    (void)ws_size;

    // CSR build
    hipMemsetAsync(deg, 0, (size_t)N * 4, stream);
    hist_kernel<<<(E + 255) / 256, 256, 0, stream>>>(dstv, deg, E);
    scan_kernel<<<1, 1024, 0, stream>>>(deg, rowptr, cursor, N);
    fill_kernel<<<(E + 255) / 256, 256, 0, stream>>>(srcv, dstv, cursor, colidx, E);

    // W pre-pack (bf16 fragment order)
    pack_kernel<<<(L * 2048 + 255) / 256, 256, 0, stream>>>(W1, Wp1, L, HD, HD * HD, 0);
    pack_kernel<<<(L * 2048 + 255) / 256, 256, 0, stream>>>(W2, Wp2, L, HD, HD * HD, 0);
    pack_kernel<<<(2 * 2048 + 255) / 256, 256, 0, stream>>>(W_out, WpO, 2, 256, 0, 128);

    // encoder
    enc_kernel<<<(N * 16 + 255) / 256, 256, 0, stream>>>(x, W_enc, b_enc, bufA, N);

    const int nblk = Npad / 128;
    ushort_t* cur = bufA;
    ushort_t* oth = bufB;
    for (int l = 0; l < L; ++l) {
        agg_kernel<<<(N * 16 + 255) / 256, 256, 0, stream>>>(cur, rowptr, colidx, oth, N);
        gemm_mfma<ushort_t, true><<<nblk, 256, 0, stream>>>(
            oth, Wp1 + (size_t)l * 16384, b1 + (size_t)l * HD, cur, HD);
        gemm_mfma<ushort_t, true><<<nblk, 256, 0, stream>>>(
            cur, Wp2 + (size_t)l * 16384, b2 + (size_t)l * HD, oth, HD);
        ushort_t* t = cur; cur = oth; oth = t;
    }

    // pooling (bf16 out, feeds final MFMA GEMM)
    pool_kernel<<<G, 128, 0, stream>>>(cur, batch, pooled, N);

    // output GEMM: [G,128] @ [128,256] + b_out -> fp32 d_out (two 128-col halves)
    float* outp = (float*)d_out;
    gemm_mfma<float, false><<<G / 128, 256, 0, stream>>>(pooled, WpO, b_out, outp, 256);
    gemm_mfma<float, false><<<G / 128, 256, 0, stream>>>(pooled, WpO + 16384, b_out + 128, outp + 128, 256);
}

// Round 5
// 590.519 us; speedup vs baseline: 2.0948x; 2.0948x over previous
//
#include <hip/hip_runtime.h>

#define HD 128   // hidden dim

typedef unsigned short ushort_t;
typedef __attribute__((ext_vector_type(8))) unsigned short us8;
typedef __attribute__((ext_vector_type(8))) short s8b;       // 8 bf16 = 4 VGPR (MFMA A/B frag)
typedef __attribute__((ext_vector_type(16))) float f32x16;   // MFMA 32x32 accumulator

// ---------------- bf16 <-> f32 ----------------
__device__ __forceinline__ float b2f(unsigned short u) {
    union { unsigned int i; float f; } v; v.i = ((unsigned int)u) << 16; return v.f;
}
__device__ __forceinline__ unsigned short f2b(float f) {
    union { float f; unsigned int i; } v; v.f = f;
    unsigned int u = v.i;
    return (unsigned short)((u + 0x7fffu + ((u >> 16) & 1u)) >> 16);  // RNE
}

__device__ __forceinline__ void load8f(const float* p, float* o) {
    float4 a = *reinterpret_cast<const float4*>(p);
    float4 b = *reinterpret_cast<const float4*>(p + 4);
    o[0]=a.x;o[1]=a.y;o[2]=a.z;o[3]=a.w;o[4]=b.x;o[5]=b.y;o[6]=b.z;o[7]=b.w;
}
__device__ __forceinline__ void load8b(const ushort_t* p, float* o) {
    us8 v = *reinterpret_cast<const us8*>(p);
#pragma unroll
    for (int j = 0; j < 8; ++j) o[j] = b2f(v[j]);
}
__device__ __forceinline__ void store8b(ushort_t* p, const float* s) {
    us8 v;
#pragma unroll
    for (int j = 0; j < 8; ++j) v[j] = f2b(s[j]);
    *reinterpret_cast<us8*>(p) = v;
}

__device__ __forceinline__ void store1(float* p, float v) { *p = v; }
__device__ __forceinline__ void store1(ushort_t* p, float v) { *p = f2b(v); }

__device__ __forceinline__ int lowerb(const int* __restrict__ a, int n, int v) {
    int lo = 0, hi = n;
    while (lo < hi) { int m = (lo + hi) >> 1; if (a[m] < v) lo = m + 1; else hi = m; }
    return lo;
}

// ---------------- CSR build ----------------
__global__ void hist_kernel(const int* __restrict__ dst, int* __restrict__ deg, int e) {
    int i = blockIdx.x * blockDim.x + threadIdx.x;
    if (i < e) atomicAdd(&deg[dst[i]], 1);
}

// 3-phase parallel exclusive scan over deg[0..n) -> rowptr/cursor
#define SCAN_NT 256
#define SCAN_BPT 8
#define SCAN_CHUNK (SCAN_NT * SCAN_BPT)   // 2048

__global__ __launch_bounds__(SCAN_NT) void scan_a(const int* __restrict__ deg,
                                                  int* __restrict__ bsum, int n) {
    int tid = threadIdx.x;
    int base = blockIdx.x * SCAN_CHUNK + tid * SCAN_BPT;
    int sum = 0;
    if (base + SCAN_BPT <= n) {
        int4 v0 = *reinterpret_cast<const int4*>(deg + base);
        int4 v1 = *reinterpret_cast<const int4*>(deg + base + 4);
        sum = v0.x + v0.y + v0.z + v0.w + v1.x + v1.y + v1.z + v1.w;
    } else {
        for (int j = 0; j < SCAN_BPT; ++j) { int i = base + j; if (i < n) sum += deg[i]; }
    }
    __shared__ int sd[SCAN_NT];
    sd[tid] = sum; __syncthreads();
    for (int off = SCAN_NT / 2; off > 0; off >>= 1) {
        if (tid < off) sd[tid] += sd[tid + off];
        __syncthreads();
    }
    if (tid == 0) bsum[blockIdx.x] = sd[0];
}

__global__ __launch_bounds__(1024) void scan_b(int* __restrict__ bsum, int nb) {
    __shared__ int ps[1024];
    int tid = threadIdx.x;
    int v = (tid < nb) ? bsum[tid] : 0;
    ps[tid] = v; __syncthreads();
    for (int off = 1; off < 1024; off <<= 1) {
        int t = (tid >= off) ? ps[tid - off] : 0;
        __syncthreads();
        ps[tid] += t;
        __syncthreads();
    }
    if (tid < nb) bsum[tid] = ps[tid] - v;   // exclusive block offsets
}

__global__ __launch_bounds__(SCAN_NT) void scan_c(const int* __restrict__ deg,
                                                  const int* __restrict__ bsum,
                                                  int* __restrict__ rowptr,
                                                  int* __restrict__ cursor,
                                                  int n, int etot) {
    int tid = threadIdx.x;
    int base = blockIdx.x * SCAN_CHUNK + tid * SCAN_BPT;
    int vals[SCAN_BPT];
    if (base + SCAN_BPT <= n) {
        int4 v0 = *reinterpret_cast<const int4*>(deg + base);
        int4 v1 = *reinterpret_cast<const int4*>(deg + base + 4);
        vals[0]=v0.x; vals[1]=v0.y; vals[2]=v0.z; vals[3]=v0.w;
        vals[4]=v1.x; vals[5]=v1.y; vals[6]=v1.z; vals[7]=v1.w;
    } else {
        for (int j = 0; j < SCAN_BPT; ++j) { int i = base + j; vals[j] = (i < n) ? deg[i] : 0; }
    }
    int sum = 0;
#pragma unroll
    for (int j = 0; j < SCAN_BPT; ++j) sum += vals[j];
    __shared__ int ps[SCAN_NT];
    ps[tid] = sum; __syncthreads();
    for (int off = 1; off < SCAN_NT; off <<= 1) {
        int t = (tid >= off) ? ps[tid - off] : 0;
        __syncthreads();
        ps[tid] += t;
        __syncthreads();
    }
    int run = bsum[blockIdx.x] + ps[tid] - sum;   // exclusive prefix for this thread
#pragma unroll
    for (int j = 0; j < SCAN_BPT; ++j) {
        int i = base + j;
        if (i < n) { rowptr[i] = run; cursor[i] = run; run += vals[j]; }
    }
    if (blockIdx.x == 0 && tid == 0) rowptr[n] = etot;
}

__global__ void fill_kernel(const int* __restrict__ src, const int* __restrict__ dst,
                            int* __restrict__ cursor, int* __restrict__ col, int e) {
    int i = blockIdx.x * blockDim.x + threadIdx.x;
    if (i < e) { int slot = atomicAdd(&cursor[dst[i]], 1); col[slot] = src[i]; }
}

// ---------------- W pre-pack into MFMA B-fragment order (bf16) ----------------
// Fragment order: flat idx = ((mat*4 + j)*8 + ks)*64 + lane, 8 bf16 each:
//   elem e = W[k = ks*16 + (lane>>5)*8 + e][n = mat*col_off + j*32 + (lane&31)]
__global__ void pack_kernel(const float* __restrict__ W, ushort_t* __restrict__ Wp,
                            int nmat, int ld, int mat_stride, int col_off) {
    int idx = blockIdx.x * blockDim.x + threadIdx.x;
    if (idx >= nmat * 2048) return;
    int lane = idx & 63;
    int ks = (idx >> 6) & 7;
    int j = (idx >> 9) & 3;
    int mat = idx >> 11;
    const float* Wm = W + (size_t)mat * mat_stride;
    int k0 = ks * 16 + (lane >> 5) * 8;
    int n = mat * col_off + j * 32 + (lane & 31);
    us8 o;
#pragma unroll
    for (int e = 0; e < 8; ++e) o[e] = f2b(Wm[(size_t)(k0 + e) * ld + n]);
    *reinterpret_cast<us8*>(Wp + (size_t)idx * 8) = o;
}

// ---------------- encoder: h = x @ W_enc + b_enc  (bf16 out) ----------------
__global__ void enc_kernel(const float* __restrict__ x, const float* __restrict__ W,
                           const float* __restrict__ b, ushort_t* __restrict__ h, int n) {
    int idx = blockIdx.x * blockDim.x + threadIdx.x;   // n*16 threads, 8 cols each
    if (idx >= n * 16) return;
    int node = idx >> 4, g = idx & 15;
    const float* xr = x + (size_t)node * 6;
    float xv[6];
#pragma unroll
    for (int d = 0; d < 6; ++d) xv[d] = xr[d];
    float acc[8];
    load8f(b + g * 8, acc);
#pragma unroll
    for (int d = 0; d < 6; ++d) {
        float w[8];
        load8f(W + d * HD + g * 8, w);
#pragma unroll
        for (int j = 0; j < 8; ++j) acc[j] += xv[d] * w[j];
    }
    store8b(h + (size_t)node * HD + g * 8, acc);
}

// ---------------- aggregation: z = h + sum_{in-neighbors} h  (bf16) ----------------
__global__ void agg_kernel(const ushort_t* __restrict__ h, const int* __restrict__ rowptr,
                           const int* __restrict__ col, ushort_t* __restrict__ z, int n) {
    int t = blockIdx.x * blockDim.x + threadIdx.x;     // n*16 threads
    int node = t >> 4;
    if (node >= n) return;
    int g = t & 15;
    float acc[8];
    load8b(h + (size_t)node * HD + g * 8, acc);
    int lo = rowptr[node], hi = rowptr[node + 1];
    for (int i = lo; i < hi; ++i) {
        int s = col[i];
        float v[8];
        load8b(h + (size_t)s * HD + g * 8, v);
#pragma unroll
        for (int j = 0; j < 8; ++j) acc[j] += v[j];
    }
    store8b(z + (size_t)node * HD + g * 8, acc);
}

// ---------------- MFMA GEMM: out = (relu?)(A[npad,128] @ W + b), A bf16, acc f32 ----------------
// 256 threads = 4 waves; wave owns 32 rows x 128 cols; block = 128 rows.
// Wp pre-packed (one 128x128 matrix, 32 KB) staged to LDS.
template<typename TO, bool RELU>
__global__ __launch_bounds__(256) void gemm_mfma(
    const ushort_t* __restrict__ A, const ushort_t* __restrict__ Wp,
    const float* __restrict__ bias, TO* __restrict__ out, int ldo)
{
    __shared__ s8b sW[2048];    // 32 KB
    const int tid = threadIdx.x;
    for (int i = tid; i < 2048; i += 256)
        sW[i] = reinterpret_cast<const s8b*>(Wp)[i];
    __syncthreads();

    const int lane = tid & 63;
    const int row0 = blockIdx.x * 128 + (tid >> 6) * 32;
    const int arow = row0 + (lane & 31);
    const int koff = (lane >> 5) * 8;

    // A fragments: lane holds row (arow), k = ks*16 + koff + [0..8)
    s8b a[8];
#pragma unroll
    for (int ks = 0; ks < 8; ++ks)
        a[ks] = *reinterpret_cast<const s8b*>(A + (size_t)arow * HD + ks * 16 + koff);

#pragma unroll
    for (int j = 0; j < 4; ++j) {
        f32x16 acc;
#pragma unroll
        for (int i = 0; i < 16; ++i) acc[i] = 0.f;
#pragma unroll
        for (int ks = 0; ks < 8; ++ks)
            acc = __builtin_amdgcn_mfma_f32_32x32x16_bf16(a[ks], sW[(j * 8 + ks) * 64 + lane], acc, 0, 0, 0);
        // C/D: col = lane&31 (+j*32), row = (reg&3) + 8*(reg>>2) + 4*(lane>>5)
        const int col = j * 32 + (lane & 31);
        const float bv = bias[col];
        const int rbase = row0 + 4 * (lane >> 5);
#pragma unroll
        for (int reg = 0; reg < 16; ++reg) {
            int row = rbase + (reg & 3) + 8 * (reg >> 2);
            float v = acc[reg] + bv;
            if (RELU) v = fmaxf(v, 0.f);
            store1(out + (size_t)row * ldo + col, v);
        }
    }
}

// ---------------- pooling: mean over sorted batch segments (bf16 in, bf16 out) ----------------
__global__ __launch_bounds__(128) void pool_kernel(const ushort_t* __restrict__ h,
                                                   const int* __restrict__ batch,
                                                   ushort_t* __restrict__ pooled, int n) {
    int g = blockIdx.x;
    int c = threadIdx.x;   // 128
    int start = lowerb(batch, n, g);
    int end = lowerb(batch, n, g + 1);
    float s = 0.f;
    for (int i = start; i < end; ++i) s += b2f(h[(size_t)i * HD + c]);
    int cnt = end - start; if (cnt < 1) cnt = 1;
    pooled[(size_t)g * HD + c] = f2b(s / (float)cnt);
}

// ---------------- entry ----------------
extern "C" void kernel_launch(void* const* d_in, const int* in_sizes, int n_in,
                              void* d_out, int out_size, void* d_ws, size_t ws_size,
                              hipStream_t stream) {
    const float* x      = (const float*)d_in[0];
    const int*   edge   = (const int*)d_in[1];
    const int*   batch  = (const int*)d_in[2];
    const float* W_enc  = (const float*)d_in[3];
    const float* b_enc  = (const float*)d_in[4];
    const float* W1     = (const float*)d_in[5];
    const float* b1     = (const float*)d_in[6];
    const float* W2     = (const float*)d_in[7];
    const float* b2     = (const float*)d_in[8];
    const float* W_out  = (const float*)d_in[9];
    const float* b_out  = (const float*)d_in[10];

    const int N = in_sizes[0] / 6;
    const int E = in_sizes[1] / 2;
    const int G = out_size / 256;
    const int L = in_sizes[5] / (HD * HD);
    const int Npad = ((N + 127) / 128) * 128;

    const int* srcv = edge;
    const int* dstv = edge + E;

    size_t off = 0;
    auto alloc = [&](size_t bytes) -> char* {
        char* p = (char*)d_ws + off;
        off += (bytes + 255) & ~(size_t)255;
        return p;
    };
    ushort_t* bufA   = (ushort_t*)alloc((size_t)Npad * HD * 2);
    ushort_t* bufB   = (ushort_t*)alloc((size_t)Npad * HD * 2);
    ushort_t* pooled = (ushort_t*)alloc((size_t)G * HD * 2);
    ushort_t* Wp1    = (ushort_t*)alloc((size_t)L * 16384 * 2);
    ushort_t* Wp2    = (ushort_t*)alloc((size_t)L * 16384 * 2);
    ushort_t* WpO    = (ushort_t*)alloc((size_t)2 * 16384 * 2);
    int* rowptr = (int*)alloc((size_t)(N + 1) * 4);
    int* cursor = (int*)alloc((size_t)N * 4);
    int* colidx = (int*)alloc((size_t)E * 4);
    int* deg    = (int*)alloc((size_t)N * 4);
    int* bsum   = (int*)alloc((size_t)1024 * 4);
    (void)ws_size;

    // CSR build (parallel 3-phase scan)
    const int nb = (N + SCAN_CHUNK - 1) / SCAN_CHUNK;
    hipMemsetAsync(deg, 0, (size_t)N * 4, stream);
    hist_kernel<<<(E + 255) / 256, 256, 0, stream>>>(dstv, deg, E);
    scan_a<<<nb, SCAN_NT, 0, stream>>>(deg, bsum, N);
    scan_b<<<1, 1024, 0, stream>>>(bsum, nb);
    scan_c<<<nb, SCAN_NT, 0, stream>>>(deg, bsum, rowptr, cursor, N, E);
    fill_kernel<<<(E + 255) / 256, 256, 0, stream>>>(srcv, dstv, cursor, colidx, E);

    // W pre-pack (bf16 fragment order)
    pack_kernel<<<(L * 2048 + 255) / 256, 256, 0, stream>>>(W1, Wp1, L, HD, HD * HD, 0);
    pack_kernel<<<(L * 2048 + 255) / 256, 256, 0, stream>>>(W2, Wp2, L, HD, HD * HD, 0);
    pack_kernel<<<(2 * 2048 + 255) / 256, 256, 0, stream>>>(W_out, WpO, 2, 256, 0, 128);

    // encoder
    enc_kernel<<<(N * 16 + 255) / 256, 256, 0, stream>>>(x, W_enc, b_enc, bufA, N);

    const int nblk = Npad / 128;
    ushort_t* cur = bufA;
    ushort_t* oth = bufB;
    for (int l = 0; l < L; ++l) {
        agg_kernel<<<(N * 16 + 255) / 256, 256, 0, stream>>>(cur, rowptr, colidx, oth, N);
        gemm_mfma<ushort_t, true><<<nblk, 256, 0, stream>>>(
            oth, Wp1 + (size_t)l * 16384, b1 + (size_t)l * HD, cur, HD);
        gemm_mfma<ushort_t, true><<<nblk, 256, 0, stream>>>(
            cur, Wp2 + (size_t)l * 16384, b2 + (size_t)l * HD, oth, HD);
        ushort_t* t = cur; cur = oth; oth = t;
    }

    // pooling (bf16 out, feeds final MFMA GEMM)
    pool_kernel<<<G, 128, 0, stream>>>(cur, batch, pooled, N);

    // output GEMM: [G,128] @ [128,256] + b_out -> fp32 d_out (two 128-col halves)
    float* outp = (float*)d_out;
    gemm_mfma<float, false><<<G / 128, 256, 0, stream>>>(pooled, WpO, b_out, outp, 256);
    gemm_mfma<float, false><<<G / 128, 256, 0, stream>>>(pooled, WpO + 16384, b_out + 128, outp + 128, 256);
}